// Round 3
// baseline (282.729 us; speedup 1.0000x reference)
//
#include <hip/hip_runtime.h>
#include <stdint.h>
#include <string.h>

// ---------------------------------------------------------------------------
// JAX threefry2x32 (20 rounds), exact reproduction of
// jax/_src/prng.py::_threefry2x32 (partitionable layout).
// Host copy used for the 64-step branch trace.
// ---------------------------------------------------------------------------
static inline uint32_t h_rotl32(uint32_t x, uint32_t r) {
  return (x << r) | (x >> (32u - r));
}

static void h_threefry2x32(uint32_t k0, uint32_t k1, uint32_t x0, uint32_t x1,
                           uint32_t& o0, uint32_t& o1) {
  const uint32_t ks2 = k0 ^ k1 ^ 0x1BD11BDAu;
  x0 += k0; x1 += k1;
  x0 += x1; x1 = h_rotl32(x1, 13); x1 ^= x0;
  x0 += x1; x1 = h_rotl32(x1, 15); x1 ^= x0;
  x0 += x1; x1 = h_rotl32(x1, 26); x1 ^= x0;
  x0 += x1; x1 = h_rotl32(x1,  6); x1 ^= x0;
  x0 += k1; x1 += ks2 + 1u;
  x0 += x1; x1 = h_rotl32(x1, 17); x1 ^= x0;
  x0 += x1; x1 = h_rotl32(x1, 29); x1 ^= x0;
  x0 += x1; x1 = h_rotl32(x1, 16); x1 ^= x0;
  x0 += x1; x1 = h_rotl32(x1, 24); x1 ^= x0;
  x0 += ks2; x1 += k0 + 2u;
  x0 += x1; x1 = h_rotl32(x1, 13); x1 ^= x0;
  x0 += x1; x1 = h_rotl32(x1, 15); x1 ^= x0;
  x0 += x1; x1 = h_rotl32(x1, 26); x1 ^= x0;
  x0 += x1; x1 = h_rotl32(x1,  6); x1 ^= x0;
  x0 += k0; x1 += k1 + 3u;
  x0 += x1; x1 = h_rotl32(x1, 17); x1 ^= x0;
  x0 += x1; x1 = h_rotl32(x1, 29); x1 ^= x0;
  x0 += x1; x1 = h_rotl32(x1, 16); x1 ^= x0;
  x0 += x1; x1 = h_rotl32(x1, 24); x1 ^= x0;
  x0 += k1; x1 += ks2 + 4u;
  x0 += x1; x1 = h_rotl32(x1, 13); x1 ^= x0;
  x0 += x1; x1 = h_rotl32(x1, 15); x1 ^= x0;
  x0 += x1; x1 = h_rotl32(x1, 26); x1 ^= x0;
  x0 += x1; x1 = h_rotl32(x1,  6); x1 ^= x0;
  o0 = x0 + ks2;
  o1 = x1 + k0 + 5u;
}

// ---------------------------------------------------------------------------
// Device: dual interleaved threefry (h-key and e-key ciphers on the same
// counter n), rotates forced to single v_alignbit_b32, fold o0^o1.
// ---------------------------------------------------------------------------
#define TF_R(x0, x1, r)                                   \
  x0 += x1;                                               \
  x1 = __builtin_amdgcn_alignbit(x1, x1, 32u - (r));      \
  x1 ^= x0;

#define TF_G(r1, r2, r3, r4)                              \
  TF_R(a0, a1, r1) TF_R(b0, b1, r1)                       \
  TF_R(a0, a1, r2) TF_R(b0, b1, r2)                       \
  TF_R(a0, a1, r3) TF_R(b0, b1, r3)                       \
  TF_R(a0, a1, r4) TF_R(b0, b1, r4)

__device__ inline void dual_tf_fold(uint32_t hk0, uint32_t hk1, uint32_t hks,
                                    uint32_t ek0, uint32_t ek1, uint32_t eks,
                                    uint32_t n, uint32_t& oh, uint32_t& oe) {
  uint32_t a0 = hk0, a1 = n + hk1;   // init key injection (x0=0, x1=n)
  uint32_t b0 = ek0, b1 = n + ek1;
  TF_G(13, 15, 26, 6)
  a0 += hk1; a1 += hks + 1u;  b0 += ek1; b1 += eks + 1u;
  TF_G(17, 29, 16, 24)
  a0 += hks; a1 += hk0 + 2u;  b0 += eks; b1 += ek0 + 2u;
  TF_G(13, 15, 26, 6)
  a0 += hk0; a1 += hk1 + 3u;  b0 += ek0; b1 += ek1 + 3u;
  TF_G(17, 29, 16, 24)
  a0 += hk1; a1 += hks + 4u;  b0 += ek1; b1 += eks + 4u;
  TF_G(13, 15, 26, 6)
  oh = (a0 + hks) ^ (a1 + hk0 + 5u);
  oe = (b0 + eks) ^ (b1 + ek0 + 5u);
}

// bits -> p*u where normal = sqrt(2)*p*u (Giles erfinv poly, XLA-compatible).
// Bit-exact u-mapping, optimized:
//   m = bits>>9 (23 bits);  f = m*2^-23 exactly (old bitcast trick)
//   u = fma(f, 2, LO) == fma(cvt_f32_u32(m), 2^-22, LO)   [identical rounding]
//   fmax(LO, u) removed: f>=0  ==>  2f+LO >= LO always (no-op).
__device__ inline float bits_to_pu(uint32_t bits) {
  const float LO = -0.99999994f;  // nextafterf(-1, 0) — matches jax uniform lo
  float c = (float)(bits >> 9);   // v_cvt_f32_u32, exact (m < 2^23)
  float u = __builtin_fmaf(c, 2.3841858e-07f, LO);  // 2^-22
  float t = u * u;
  float w = -__logf(1.0f - t);
  float p;
  if (w < 5.0f) {
    float ww = w - 2.5f;
    p = 2.81022636e-08f;
    p = __builtin_fmaf(p, ww, 3.43273939e-07f);
    p = __builtin_fmaf(p, ww, -3.5233877e-06f);
    p = __builtin_fmaf(p, ww, -4.39150654e-06f);
    p = __builtin_fmaf(p, ww, 0.00021858087f);
    p = __builtin_fmaf(p, ww, -0.00125372503f);
    p = __builtin_fmaf(p, ww, -0.00417768164f);
    p = __builtin_fmaf(p, ww, 0.246640727f);
    p = __builtin_fmaf(p, ww, 1.50140941f);
  } else {
    float ww = sqrtf(w) - 3.0f;
    p = -0.000200214257f;
    p = __builtin_fmaf(p, ww, 0.000100950558f);
    p = __builtin_fmaf(p, ww, 0.00134934322f);
    p = __builtin_fmaf(p, ww, -0.00367342844f);
    p = __builtin_fmaf(p, ww, 0.00573950773f);
    p = __builtin_fmaf(p, ww, -0.0076224613f);
    p = __builtin_fmaf(p, ww, 0.00943887047f);
    p = __builtin_fmaf(p, ww, 1.00167406f);
    p = __builtin_fmaf(p, ww, 2.83297682f);
  }
  return p * u;
}

// out[n] = FS * (pu_h + pu_e),  FS = sqrt(2)*scale (host-folded).
// 8 elements per thread (two float4 stores) to amortize loop/address overhead.
__global__ __launch_bounds__(256) void gen_kernel(
    float* __restrict__ out, uint32_t kh0, uint32_t kh1, uint32_t khs,
    uint32_t ke0, uint32_t ke1, uint32_t kes, float FS, int n8) {
  int t = blockIdx.x * 256 + threadIdx.x;
  if (t >= n8) return;
  uint32_t base = (uint32_t)t * 8u;
  float v[8];
#pragma unroll
  for (int j = 0; j < 8; ++j) {
    uint32_t oh, oe;
    dual_tf_fold(kh0, kh1, khs, ke0, ke1, kes, base + (uint32_t)j, oh, oe);
    v[j] = FS * (bits_to_pu(oh) + bits_to_pu(oe));
  }
  float4 o0, o1;
  o0.x = v[0]; o0.y = v[1]; o0.z = v[2]; o0.w = v[3];
  o1.x = v[4]; o1.y = v[5]; o1.z = v[6]; o1.w = v[7];
  float4* outv = reinterpret_cast<float4*>(out) + (size_t)t * 2;
  outv[0] = o0;
  outv[1] = o1;
}

// fallback: all branches False -> out = (h + e) * 0.7^64
__global__ __launch_bounds__(256) void blend_kernel(
    const float4* __restrict__ a, const float4* __restrict__ b,
    float4* __restrict__ out, float s, int n4) {
  int t = blockIdx.x * 256 + threadIdx.x;
  if (t >= n4) return;
  float4 x = a[t], y = b[t];
  float4 o;
  o.x = (x.x + y.x) * s;
  o.y = (x.y + y.y) * s;
  o.z = (x.z + y.z) * s;
  o.w = (x.w + y.w) * s;
  out[t] = o;
}

extern "C" void kernel_launch(void* const* d_in, const int* in_sizes, int n_in,
                              void* d_out, int out_size, void* d_ws,
                              size_t ws_size, hipStream_t stream) {
  const float* h_in = (const float*)d_in[0];
  const float* e_in = (const float*)d_in[1];
  float* out = (float*)d_out;

  // Host-side deterministic trace of the 64 scan steps (identical every call).
  // base key = jax.random.key(42) -> (0, 42); partitionable split:
  // key_i = enc(key; 0, i); split(key_i,3) -> counters 0,1,2;
  // uniform bits = lane0 ^ lane1 of enc(kb; 0, 0).
  const uint32_t bk0 = 0u, bk1 = 42u;
  int last_true = -1;
  uint32_t kh0 = 0, kh1 = 0, ke0 = 0, ke1 = 0;
  for (uint32_t i = 0; i < 64; ++i) {
    uint32_t ki0, ki1;
    h_threefry2x32(bk0, bk1, 0u, i, ki0, ki1);
    uint32_t kb0, kb1, tkh0, tkh1, tke0, tke1;
    h_threefry2x32(ki0, ki1, 0u, 0u, kb0, kb1);
    h_threefry2x32(ki0, ki1, 0u, 1u, tkh0, tkh1);
    h_threefry2x32(ki0, ki1, 0u, 2u, tke0, tke1);
    uint32_t ub0, ub1;
    h_threefry2x32(kb0, kb1, 0u, 0u, ub0, ub1);
    uint32_t bits = ub0 ^ ub1;
    uint32_t fb = (bits >> 9) | 0x3f800000u;
    float f;
    memcpy(&f, &fb, 4);
    f -= 1.0f;  // uniform in [0,1)
    if (f < 0.5f) {  // RAND_RATIO
      last_true = (int)i;
      kh0 = tkh0; kh1 = tkh1; ke0 = tke0; ke1 = tke1;
    }
  }

  if (last_true >= 0) {
    const int c = 63 - last_true;
    float scale = 1.0f;
    for (int j = 0; j < c; ++j) scale *= 0.7f;
    const float FS = 1.41421356f * scale;
    const uint32_t khs = kh0 ^ kh1 ^ 0x1BD11BDAu;
    const uint32_t kes = ke0 ^ ke1 ^ 0x1BD11BDAu;
    const int n8 = out_size / 8;
    const int grid = (n8 + 255) / 256;
    gen_kernel<<<grid, 256, 0, stream>>>(out, kh0, kh1, khs, ke0, ke1, kes, FS,
                                         n8);
  } else {
    float scale = 1.0f;
    for (int j = 0; j < 64; ++j) scale *= 0.7f;
    const int n4 = out_size / 4;
    const int grid = (n4 + 255) / 256;
    blend_kernel<<<grid, 256, 0, stream>>>(
        (const float4*)h_in, (const float4*)e_in, (float4*)out, scale, n4);
  }
}